// Round 1
// baseline (204.202 us; speedup 1.0000x reference)
//
#include <hip/hip_runtime.h>
#include <hip/hip_bf16.h>

#define NH 32
#define DH 128
#define DIMM 4096
#define TCTX 16384
#define BSZ 8
#define NBLK_TOT (TCTX / BSZ)   // 2048
#define MB_SEL 145
#define SINK_TOK 60
#define WIN_TOK 60
#define BLK_CAP 192             // >= 161, padded

// ---------------- GEMV: out[row] = dot(w[row][:], x[:]) ----------------
// one wave per row, 4 rows per workgroup, x staged in LDS
__global__ __launch_bounds__(256) void k_gemv(const float* __restrict__ x,
                                              const float* __restrict__ w,
                                              float* __restrict__ out) {
    __shared__ float xs[DIMM];
    int t = threadIdx.x;
    for (int i = t; i < DIMM / 4; i += 256)
        ((float4*)xs)[i] = ((const float4*)x)[i];
    __syncthreads();
    int wave = t >> 6, lane = t & 63;
    int row = blockIdx.x * 4 + wave;
    const float* wr = w + (size_t)row * DIMM;
    float acc = 0.f;
    #pragma unroll
    for (int it = 0; it < 16; ++it) {
        int j = lane * 4 + it * 256;
        float4 wv = *(const float4*)(wr + j);
        float4 xv = *(const float4*)(xs + j);
        acc += wv.x * xv.x + wv.y * xv.y + wv.z * xv.z + wv.w * xv.w;
    }
    #pragma unroll
    for (int m = 1; m < 64; m <<= 1) acc += __shfl_xor(acc, m, 64);
    if (lane == 0) out[row] = acc;
}

// ---------------- RoPE + split qkv -> q1, k_new, v_new ----------------
// 6144 threads: t<2048 q pairs, 2048..4095 k pairs, 4096..6143 v pairs (copy)
__global__ void k_rope(const float* __restrict__ qkv,
                       const float* __restrict__ freqs,
                       float* __restrict__ q1, float* __restrict__ kn,
                       float* __restrict__ vn) {
    int t = blockIdx.x * blockDim.x + threadIdx.x;
    if (t >= 6144) return;
    if (t < 4096) {
        float x0 = qkv[2 * t], x1 = qkv[2 * t + 1];
        int m = t & 63;  // pair index within head
        float fr = freqs[2 * m], fi = freqs[2 * m + 1];
        float o0 = x0 * fr - x1 * fi;
        float o1 = x1 * fr + x0 * fi;
        if (t < 2048) { q1[2 * t] = o0; q1[2 * t + 1] = o1; }
        else { kn[2 * t - 4096] = o0; kn[2 * t - 4095] = o1; }
    } else {
        int i = t - 4096;
        vn[2 * i]     = qkv[8192 + 2 * i];
        vn[2 * i + 1] = qkv[8192 + 2 * i + 1];
    }
}

// ---------------- block-mean scores: one wave per (head, 8-token block) ----
__global__ __launch_bounds__(256) void k_scores(const float* __restrict__ q1,
                                                const float* __restrict__ kc,
                                                const int* __restrict__ ip_p,
                                                float* __restrict__ scores) {
    int ip = *ip_p;
    int T = ip + 1;
    int Tb = T / BSZ;
    int wave = threadIdx.x >> 6, lane = threadIdx.x & 63;
    int h = blockIdx.x >> 9;                 // 512 WGs per head
    int blk = ((blockIdx.x & 511) << 2) + wave;
    if (blk >= Tb) {
        if (blk < NBLK_TOT && lane == 0) scores[h * NBLK_TOT + blk] = -1e30f;
        return;
    }
    int d0 = (lane * 4) & 127;
    float4 q4 = *(const float4*)(q1 + h * DH + d0);
    const float* kb = kc + ((size_t)h * TCTX + (size_t)blk * BSZ) * DH;
    float acc = 0.f;
    #pragma unroll
    for (int i = 0; i < 4; ++i) {
        float4 k4 = *(const float4*)(kb + lane * 4 + i * 256);
        acc += q4.x * k4.x + q4.y * k4.y + q4.z * k4.z + q4.w * k4.w;
    }
    #pragma unroll
    for (int m = 1; m < 64; m <<= 1) acc += __shfl_xor(acc, m, 64);
    // score = (q . mean_k) * 1/sqrt(128) = acc * (1/(8*sqrt(128)))
    if (lane == 0) scores[h * NBLK_TOT + blk] = acc * 0.011048543456039805f;
}

// ---------------- top-k selection per head ----------------
__global__ __launch_bounds__(256) void k_topk(const float* __restrict__ scores,
                                              const int* __restrict__ ip_p,
                                              int* __restrict__ blklist) {
    __shared__ unsigned int U[NBLK_TOT];
    __shared__ int red[4];
    __shared__ int bc;
    __shared__ unsigned int scan[256];
    int t = threadIdx.x, h = blockIdx.x;
    int wave = t >> 6, lane = t & 63;
    int ip = *ip_p;
    int T = ip + 1;
    int Tb = T / BSZ;
    int sink_b = min((min(SINK_TOK, T) + BSZ - 1) / BSZ, Tb);
    int window_b = min((min(WIN_TOK, T) + BSZ - 1) / BSZ, Tb);
    int cur = (T - 1) / BSZ;
    int win_start = max(0, cur - window_b + 1);
    int win_end = cur + 1;

    // load + map to sortable uint; excluded -> 0
    for (int j = t * 8; j < t * 8 + 8; ++j) {
        unsigned int u = 0u;
        if (j < Tb && j >= sink_b && !(j >= win_start && j < win_end)) {
            unsigned int b = __float_as_uint(scores[h * NBLK_TOT + j]);
            u = (b & 0x80000000u) ? ~b : (b | 0x80000000u);
        }
        U[j] = u;
    }
    __syncthreads();

    // binary search for the MB_SEL-th largest value
    unsigned int lo = 0u, hi = 0xFFFFFFFFu;
    while (lo < hi) {
        unsigned int mid =
            (unsigned int)(((unsigned long long)lo + (unsigned long long)hi + 1ull) >> 1);
        int c = 0;
        for (int j = t * 8; j < t * 8 + 8; ++j) c += (U[j] >= mid);
        #pragma unroll
        for (int m = 1; m < 64; m <<= 1) c += __shfl_xor(c, m, 64);
        if (lane == 0) red[wave] = c;
        __syncthreads();
        if (t == 0) bc = red[0] + red[1] + red[2] + red[3];
        __syncthreads();
        if (bc >= MB_SEL) lo = mid; else hi = mid - 1;
        __syncthreads();
    }

    // compact: strictly-greater first, then ties by lowest index
    unsigned int gt = 0, eq = 0;
    for (int j = t * 8; j < t * 8 + 8; ++j) {
        gt += (U[j] > lo);
        eq += (U[j] == lo);
    }
    unsigned int packed = (gt << 16) | eq;
    scan[t] = packed;
    __syncthreads();
    for (int off = 1; off < 256; off <<= 1) {
        unsigned int v = scan[t] + ((t >= off) ? scan[t - off] : 0u);
        __syncthreads();
        scan[t] = v;
        __syncthreads();
    }
    unsigned int totg = scan[255] >> 16;
    unsigned int exclp = scan[t] - packed;
    unsigned int pg = exclp >> 16, pe = exclp & 0xFFFFu;
    int need_eq = MB_SEL - (int)totg;

    int base = sink_b + (win_end - win_start);
    int* bl = blklist + h * BLK_CAP;
    if (t < sink_b) bl[t] = t;
    if (t >= sink_b && t < base) bl[t] = win_start + (t - sink_b);

    unsigned int gi = pg, ei = pe;
    for (int j = t * 8; j < t * 8 + 8; ++j) {
        if (U[j] > lo) {
            bl[base + (int)gi] = j; ++gi;
        } else if (U[j] == lo) {
            if ((int)ei < need_eq) bl[base + (int)totg + (int)ei] = j;
            ++ei;
        }
    }
}

// ---------------- gathered attention, one workgroup per head ----------------
__global__ __launch_bounds__(256) void k_attn(const float* __restrict__ q1,
                                              const float* __restrict__ kc,
                                              const float* __restrict__ vc,
                                              const float* __restrict__ kn,
                                              const float* __restrict__ vn,
                                              const int* __restrict__ blklist,
                                              const int* __restrict__ ip_p,
                                              float* __restrict__ o) {
    __shared__ float att[1312];
    __shared__ float oacc[4][DH];
    __shared__ float redm[4];
    __shared__ int bl_s[BLK_CAP];
    int h = blockIdx.x;
    int t = threadIdx.x, wave = t >> 6, lane = t & 63;
    int g = lane >> 4, sub = lane & 15;
    int ip = *ip_p;
    int T = ip + 1;
    int Tb = T / BSZ;
    int sink_b = min((min(SINK_TOK, T) + BSZ - 1) / BSZ, Tb);
    int window_b = min((min(WIN_TOK, T) + BSZ - 1) / BSZ, Tb);
    int cur = (T - 1) / BSZ;
    int win_start = max(0, cur - window_b + 1);
    int nwin = cur + 1 - win_start;
    int nblk = sink_b + nwin + MB_SEL;   // 161
    int N = nblk * BSZ;                   // 1288

    if (t < nblk) bl_s[t] = blklist[h * BLK_CAP + t];
    __syncthreads();

    float4 qa = *(const float4*)(q1 + h * DH + sub * 8);
    float4 qb = *(const float4*)(q1 + h * DH + sub * 8 + 4);
    const float* kh = kc + (size_t)h * TCTX * DH;
    const float* vh = vc + (size_t)h * TCTX * DH;

    // phase A: scores. 4 tokens per wave-pass (16 lanes per token)
    for (int c = wave; c < N / 4; c += 4) {
        int blk = bl_s[c >> 1];
        int tok = blk * BSZ + (c & 1) * 4 + g;
        const float* kr = (tok == ip) ? (kn + h * DH) : (kh + (size_t)tok * DH);
        float4 ka = *(const float4*)(kr + sub * 8);
        float4 kb2 = *(const float4*)(kr + sub * 8 + 4);
        float p = qa.x * ka.x + qa.y * ka.y + qa.z * ka.z + qa.w * ka.w +
                  qb.x * kb2.x + qb.y * kb2.y + qb.z * kb2.z + qb.w * kb2.w;
        p += __shfl_xor(p, 1, 64);
        p += __shfl_xor(p, 2, 64);
        p += __shfl_xor(p, 4, 64);
        p += __shfl_xor(p, 8, 64);
        if (sub == 0) att[c * 4 + g] = p * 0.08838834764831845f;
    }
    __syncthreads();

    // softmax
    float mx = -1e30f;
    for (int n = t; n < N; n += 256) mx = fmaxf(mx, att[n]);
    #pragma unroll
    for (int m = 1; m < 64; m <<= 1) mx = fmaxf(mx, __shfl_xor(mx, m, 64));
    if (lane == 0) redm[wave] = mx;
    __syncthreads();
    mx = fmaxf(fmaxf(redm[0], redm[1]), fmaxf(redm[2], redm[3]));
    __syncthreads();
    float sum = 0.f;
    for (int n = t; n < N; n += 256) {
        float e = __expf(att[n] - mx);
        att[n] = e;
        sum += e;
    }
    #pragma unroll
    for (int m = 1; m < 64; m <<= 1) sum += __shfl_xor(sum, m, 64);
    if (lane == 0) redm[wave] = sum;
    __syncthreads();
    sum = redm[0] + redm[1] + redm[2] + redm[3];
    float inv = 1.0f / sum;

    // phase B: weighted V accumulation
    float4 aa = make_float4(0, 0, 0, 0), ab = make_float4(0, 0, 0, 0);
    for (int c = wave; c < N / 4; c += 4) {
        int blk = bl_s[c >> 1];
        int tok = blk * BSZ + (c & 1) * 4 + g;
        const float* vr = (tok == ip) ? (vn + h * DH) : (vh + (size_t)tok * DH);
        float p = att[c * 4 + g];
        float4 va = *(const float4*)(vr + sub * 8);
        float4 vb = *(const float4*)(vr + sub * 8 + 4);
        aa.x += p * va.x; aa.y += p * va.y; aa.z += p * va.z; aa.w += p * va.w;
        ab.x += p * vb.x; ab.y += p * vb.y; ab.z += p * vb.z; ab.w += p * vb.w;
    }
    #pragma unroll
    for (int m = 16; m < 64; m <<= 1) {
        aa.x += __shfl_xor(aa.x, m, 64); aa.y += __shfl_xor(aa.y, m, 64);
        aa.z += __shfl_xor(aa.z, m, 64); aa.w += __shfl_xor(aa.w, m, 64);
        ab.x += __shfl_xor(ab.x, m, 64); ab.y += __shfl_xor(ab.y, m, 64);
        ab.z += __shfl_xor(ab.z, m, 64); ab.w += __shfl_xor(ab.w, m, 64);
    }
    if (g == 0) {
        oacc[wave][sub * 8 + 0] = aa.x; oacc[wave][sub * 8 + 1] = aa.y;
        oacc[wave][sub * 8 + 2] = aa.z; oacc[wave][sub * 8 + 3] = aa.w;
        oacc[wave][sub * 8 + 4] = ab.x; oacc[wave][sub * 8 + 5] = ab.y;
        oacc[wave][sub * 8 + 6] = ab.z; oacc[wave][sub * 8 + 7] = ab.w;
    }
    __syncthreads();
    if (t < DH) {
        float s = oacc[0][t] + oacc[1][t] + oacc[2][t] + oacc[3][t];
        o[h * DH + t] = s * inv;
    }
}

extern "C" void kernel_launch(void* const* d_in, const int* in_sizes, int n_in,
                              void* d_out, int out_size, void* d_ws, size_t ws_size,
                              hipStream_t stream) {
    const float* x     = (const float*)d_in[0];
    const float* freqs = (const float*)d_in[1];
    const float* wqkv  = (const float*)d_in[2];
    const float* wo    = (const float*)d_in[3];
    const float* kc    = (const float*)d_in[4];
    const float* vc    = (const float*)d_in[5];
    const int*   ip    = (const int*)d_in[6];
    float* y = (float*)d_out;

    float* ws     = (float*)d_ws;
    float* qkv    = ws;              // 12288
    float* q1     = ws + 12288;      // 4096
    float* kn     = ws + 16384;      // 4096
    float* vn     = ws + 20480;      // 4096
    float* scores = ws + 24576;      // 65536
    float* o      = ws + 90112;      // 4096
    int*   blkl   = (int*)(ws + 94208);  // 32*192 ints

    // 1) qkv = x @ wqkv.T   (12288 rows)
    k_gemv<<<12288 / 4, 256, 0, stream>>>(x, wqkv, qkv);
    // 2) RoPE + split
    k_rope<<<24, 256, 0, stream>>>(qkv, freqs, q1, kn, vn);
    // 3) block-mean scores (32 heads * 2048 blocks, 4 blocks per WG)
    k_scores<<<NH * 512, 256, 0, stream>>>(q1, kc, ip, scores);
    // 4) per-head top-k block selection
    k_topk<<<NH, 256, 0, stream>>>(scores, ip, blkl);
    // 5) gathered attention
    k_attn<<<NH, 256, 0, stream>>>(q1, kc, vc, kn, vn, blkl, ip, o);
    // 6) y = o @ wo.T   (4096 rows)
    k_gemv<<<DIMM / 4, 256, 0, stream>>>(o, wo, y);
}

// Round 2
// 135.551 us; speedup vs baseline: 1.5065x; 1.5065x over previous
//
#include <hip/hip_runtime.h>
#include <hip/hip_bf16.h>

#define NH 32
#define DH 128
#define DIMM 4096
#define TCTX 16384
#define BSZ 8
#define NBLK_TOT (TCTX / BSZ)   // 2048
#define MB_SEL 145
#define SINK_TOK 60
#define WIN_TOK 60
#define BLK_CAP 192             // >= 161, padded
#define NSPLIT 8
#define PSTRIDE (DH + 2)        // per-(head,split) partial: o[128], m, l

// ---------------- QKV GEMV + fused RoPE epilogue ----------------
// one wave per output row, 4 rows per workgroup, x staged in LDS.
// rows [0,4096) -> q1 (rope), [4096,8192) -> kn (rope), [8192,12288) -> vn
__global__ __launch_bounds__(256) void k_gemv_qkv(const float* __restrict__ x,
                                                  const float* __restrict__ w,
                                                  const float* __restrict__ freqs,
                                                  float* __restrict__ q1,
                                                  float* __restrict__ kn,
                                                  float* __restrict__ vn) {
    __shared__ float xs[DIMM];
    __shared__ float acc4[4];
    int t = threadIdx.x;
    for (int i = t; i < DIMM / 4; i += 256)
        ((float4*)xs)[i] = ((const float4*)x)[i];
    __syncthreads();
    int wave = t >> 6, lane = t & 63;
    int row = blockIdx.x * 4 + wave;
    const float* wr = w + (size_t)row * DIMM;
    float acc = 0.f;
    #pragma unroll
    for (int it = 0; it < 16; ++it) {
        int j = lane * 4 + it * 256;
        float4 wv = *(const float4*)(wr + j);
        float4 xv = *(const float4*)(xs + j);
        acc += wv.x * xv.x + wv.y * xv.y + wv.z * xv.z + wv.w * xv.w;
    }
    #pragma unroll
    for (int m = 1; m < 64; m <<= 1) acc += __shfl_xor(acc, m, 64);
    if (lane == 0) acc4[wave] = acc;
    __syncthreads();
    if (t < 4) {
        int r = blockIdx.x * 4 + t;
        float a = acc4[t];
        if (r < 2 * DIMM) {
            float b = acc4[t ^ 1];
            int m = (r >> 1) & 63;
            float fr = freqs[2 * m], fi = freqs[2 * m + 1];
            // even row holds x0: o0 = x0*fr - x1*fi ; odd row holds x1: o1 = x1*fr + x0*fi
            float o = ((r & 1) == 0) ? (a * fr - b * fi) : (a * fr + b * fi);
            if (r < DIMM) q1[r] = o; else kn[r - DIMM] = o;
        } else {
            vn[r - 2 * DIMM] = a;
        }
    }
}

// ---------------- plain GEMV for the output projection ----------------
__global__ __launch_bounds__(256) void k_gemv_o(const float* __restrict__ x,
                                                const float* __restrict__ w,
                                                float* __restrict__ out) {
    __shared__ float xs[DIMM];
    int t = threadIdx.x;
    for (int i = t; i < DIMM / 4; i += 256)
        ((float4*)xs)[i] = ((const float4*)x)[i];
    __syncthreads();
    int wave = t >> 6, lane = t & 63;
    int row = blockIdx.x * 4 + wave;
    const float* wr = w + (size_t)row * DIMM;
    float acc = 0.f;
    #pragma unroll
    for (int it = 0; it < 16; ++it) {
        int j = lane * 4 + it * 256;
        float4 wv = *(const float4*)(wr + j);
        float4 xv = *(const float4*)(xs + j);
        acc += wv.x * xv.x + wv.y * xv.y + wv.z * xv.z + wv.w * xv.w;
    }
    #pragma unroll
    for (int m = 1; m < 64; m <<= 1) acc += __shfl_xor(acc, m, 64);
    if (lane == 0) out[row] = acc;
}

// ---------------- block-mean scores: one wave per (head, 8-token block) ----
__global__ __launch_bounds__(256) void k_scores(const float* __restrict__ q1,
                                                const float* __restrict__ kc,
                                                const int* __restrict__ ip_p,
                                                float* __restrict__ scores) {
    int ip = *ip_p;
    int T = ip + 1;
    int Tb = T / BSZ;
    int wave = threadIdx.x >> 6, lane = threadIdx.x & 63;
    int h = blockIdx.x >> 9;                 // 512 WGs per head
    int blk = ((blockIdx.x & 511) << 2) + wave;
    if (blk >= Tb) {
        if (blk < NBLK_TOT && lane == 0) scores[h * NBLK_TOT + blk] = -1e30f;
        return;
    }
    int d0 = (lane * 4) & 127;
    float4 q4 = *(const float4*)(q1 + h * DH + d0);
    const float* kb = kc + ((size_t)h * TCTX + (size_t)blk * BSZ) * DH;
    float acc = 0.f;
    #pragma unroll
    for (int i = 0; i < 4; ++i) {
        float4 k4 = *(const float4*)(kb + lane * 4 + i * 256);
        acc += q4.x * k4.x + q4.y * k4.y + q4.z * k4.z + q4.w * k4.w;
    }
    #pragma unroll
    for (int m = 1; m < 64; m <<= 1) acc += __shfl_xor(acc, m, 64);
    // score = (q . mean_k) * 1/sqrt(128) = acc * (1/(8*sqrt(128)))
    if (lane == 0) scores[h * NBLK_TOT + blk] = acc * 0.011048543456039805f;
}

// ---------------- top-k selection: ONE WAVE per head, all in registers ----
__global__ __launch_bounds__(64) void k_topk(const float* __restrict__ scores,
                                             const int* __restrict__ ip_p,
                                             int* __restrict__ blklist) {
    int h = blockIdx.x;
    int lane = threadIdx.x & 63;
    int ip = *ip_p;
    int T = ip + 1;
    int Tb = T / BSZ;
    int sink_b = min((min(SINK_TOK, T) + BSZ - 1) / BSZ, Tb);
    int window_b = min((min(WIN_TOK, T) + BSZ - 1) / BSZ, Tb);
    int cur = (T - 1) / BSZ;
    int win_start = max(0, cur - window_b + 1);
    int win_end = cur + 1;

    // lane owns contiguous indices [lane*32, lane*32+32) -> lane order == index order
    unsigned int u[32];
    const float* sh = scores + h * NBLK_TOT;
    #pragma unroll
    for (int i = 0; i < 32; i += 4) {
        float4 sv = *(const float4*)(sh + lane * 32 + i);
        float fv[4] = {sv.x, sv.y, sv.z, sv.w};
        #pragma unroll
        for (int q = 0; q < 4; ++q) {
            int j = lane * 32 + i + q;
            unsigned int b = __float_as_uint(fv[q]);
            unsigned int m = (b & 0x80000000u) ? ~b : (b | 0x80000000u);
            bool ok = (j < Tb) && (j >= sink_b) && !(j >= win_start && j < win_end);
            u[i + q] = ok ? m : 0u;
        }
    }

    // binary search for the MB_SEL-th largest mapped value (no barriers)
    unsigned int lo = 0u, hi = 0xFFFFFFFFu;
    while (lo < hi) {
        unsigned int mid =
            (unsigned int)(((unsigned long long)lo + (unsigned long long)hi + 1ull) >> 1);
        int c = 0;
        #pragma unroll
        for (int i = 0; i < 32; ++i) c += (u[i] >= mid);
        #pragma unroll
        for (int m = 1; m < 64; m <<= 1) c += __shfl_xor(c, m, 64);
        if (c >= MB_SEL) lo = mid; else hi = mid - 1;
    }

    // compact: strictly-greater first, then ties by lowest index
    int gt = 0, eq = 0;
    #pragma unroll
    for (int i = 0; i < 32; ++i) { gt += (u[i] > lo); eq += (u[i] == lo); }
    unsigned int packed = ((unsigned int)gt << 16) | (unsigned int)eq;
    unsigned int sc = packed;
    #pragma unroll
    for (int off = 1; off < 64; off <<= 1) {
        unsigned int v = __shfl_up(sc, off, 64);
        if (lane >= off) sc += v;
    }
    unsigned int tot = __shfl(sc, 63, 64);
    unsigned int totg = tot >> 16;
    unsigned int excl = sc - packed;
    int gi = (int)(excl >> 16);
    int ei = (int)(excl & 0xFFFFu);
    int need_eq = MB_SEL - (int)totg;

    int base = sink_b + (win_end - win_start);
    int* bl = blklist + h * BLK_CAP;
    for (int i = lane; i < base; i += 64)
        bl[i] = (i < sink_b) ? i : (win_start + (i - sink_b));

    #pragma unroll
    for (int i = 0; i < 32; ++i) {
        int j = lane * 32 + i;
        if (u[i] > lo) {
            bl[base + gi] = j; ++gi;
        } else if (u[i] == lo) {
            if (ei < need_eq) bl[base + (int)totg + ei] = j;
            ++ei;
        }
    }
}

// ---------------- gathered attention, flash-decode split ----------------
// grid = NH * NSPLIT; each WG does ~21 blocks, emits unnormalized partial
__global__ __launch_bounds__(256) void k_attn_part(const float* __restrict__ q1,
                                                   const float* __restrict__ kc,
                                                   const float* __restrict__ vc,
                                                   const float* __restrict__ kn,
                                                   const float* __restrict__ vn,
                                                   const int* __restrict__ blklist,
                                                   const int* __restrict__ ip_p,
                                                   float* __restrict__ part) {
    __shared__ float att[176];
    __shared__ float oacc[4][DH];
    __shared__ float redm[4];
    __shared__ int bl_s[24];
    int h = blockIdx.x / NSPLIT;
    int sp = blockIdx.x % NSPLIT;
    int t = threadIdx.x, wave = t >> 6, lane = t & 63;
    int g = lane >> 4, sub = lane & 15;
    int ip = *ip_p;
    int T = ip + 1;
    int Tb = T / BSZ;
    int sink_b = min((min(SINK_TOK, T) + BSZ - 1) / BSZ, Tb);
    int window_b = min((min(WIN_TOK, T) + BSZ - 1) / BSZ, Tb);
    int cur = (T - 1) / BSZ;
    int win_start = max(0, cur - window_b + 1);
    int nwin = cur + 1 - win_start;
    int nblk = sink_b + nwin + MB_SEL;            // 161
    int chunk = (nblk + NSPLIT - 1) / NSPLIT;     // 21
    int b0 = sp * chunk;
    int nb = min(nblk - b0, chunk);
    if (nb <= 0) nb = 0;                          // (not hit at 161/8)
    int Ns = nb * BSZ;

    if (t < nb) bl_s[t] = blklist[h * BLK_CAP + b0 + t];
    __syncthreads();

    float4 qa = *(const float4*)(q1 + h * DH + sub * 8);
    float4 qb = *(const float4*)(q1 + h * DH + sub * 8 + 4);
    const float* kh = kc + (size_t)h * TCTX * DH;
    const float* vh = vc + (size_t)h * TCTX * DH;

    // phase A: scores (16 lanes per token, 4 tokens per wave-pass)
    for (int c = wave; c < nb * 2; c += 4) {
        int blk = bl_s[c >> 1];
        int tok = blk * BSZ + (c & 1) * 4 + g;
        const float* kr = (tok == ip) ? (kn + h * DH) : (kh + (size_t)tok * DH);
        float4 ka = *(const float4*)(kr + sub * 8);
        float4 kb2 = *(const float4*)(kr + sub * 8 + 4);
        float p = qa.x * ka.x + qa.y * ka.y + qa.z * ka.z + qa.w * ka.w +
                  qb.x * kb2.x + qb.y * kb2.y + qb.z * kb2.z + qb.w * kb2.w;
        p += __shfl_xor(p, 1, 64);
        p += __shfl_xor(p, 2, 64);
        p += __shfl_xor(p, 4, 64);
        p += __shfl_xor(p, 8, 64);
        if (sub == 0) att[c * 4 + g] = p * 0.08838834764831845f;
    }
    __syncthreads();

    // local softmax (unnormalized partial)
    float mx = -1e30f;
    for (int n = t; n < Ns; n += 256) mx = fmaxf(mx, att[n]);
    #pragma unroll
    for (int m = 1; m < 64; m <<= 1) mx = fmaxf(mx, __shfl_xor(mx, m, 64));
    if (lane == 0) redm[wave] = mx;
    __syncthreads();
    mx = fmaxf(fmaxf(redm[0], redm[1]), fmaxf(redm[2], redm[3]));
    __syncthreads();
    float sum = 0.f;
    for (int n = t; n < Ns; n += 256) {
        float e = __expf(att[n] - mx);
        att[n] = e;
        sum += e;
    }
    #pragma unroll
    for (int m = 1; m < 64; m <<= 1) sum += __shfl_xor(sum, m, 64);
    if (lane == 0) redm[wave] = sum;
    __syncthreads();
    float lsum = redm[0] + redm[1] + redm[2] + redm[3];

    // phase B: weighted V accumulation (unnormalized)
    float4 aa = make_float4(0, 0, 0, 0), ab = make_float4(0, 0, 0, 0);
    for (int c = wave; c < nb * 2; c += 4) {
        int blk = bl_s[c >> 1];
        int tok = blk * BSZ + (c & 1) * 4 + g;
        const float* vr = (tok == ip) ? (vn + h * DH) : (vh + (size_t)tok * DH);
        float p = att[c * 4 + g];
        float4 va = *(const float4*)(vr + sub * 8);
        float4 vb = *(const float4*)(vr + sub * 8 + 4);
        aa.x += p * va.x; aa.y += p * va.y; aa.z += p * va.z; aa.w += p * va.w;
        ab.x += p * vb.x; ab.y += p * vb.y; ab.z += p * vb.z; ab.w += p * vb.w;
    }
    #pragma unroll
    for (int m = 16; m < 64; m <<= 1) {
        aa.x += __shfl_xor(aa.x, m, 64); aa.y += __shfl_xor(aa.y, m, 64);
        aa.z += __shfl_xor(aa.z, m, 64); aa.w += __shfl_xor(aa.w, m, 64);
        ab.x += __shfl_xor(ab.x, m, 64); ab.y += __shfl_xor(ab.y, m, 64);
        ab.z += __shfl_xor(ab.z, m, 64); ab.w += __shfl_xor(ab.w, m, 64);
    }
    if (g == 0) {
        oacc[wave][sub * 8 + 0] = aa.x; oacc[wave][sub * 8 + 1] = aa.y;
        oacc[wave][sub * 8 + 2] = aa.z; oacc[wave][sub * 8 + 3] = aa.w;
        oacc[wave][sub * 8 + 4] = ab.x; oacc[wave][sub * 8 + 5] = ab.y;
        oacc[wave][sub * 8 + 6] = ab.z; oacc[wave][sub * 8 + 7] = ab.w;
    }
    __syncthreads();
    float* pp = part + ((size_t)h * NSPLIT + sp) * PSTRIDE;
    if (t < DH)
        pp[t] = oacc[0][t] + oacc[1][t] + oacc[2][t] + oacc[3][t];
    if (t == DH)     pp[DH] = mx;
    if (t == DH + 1) pp[DH + 1] = lsum;
}

// ---------------- combine partials ----------------
__global__ __launch_bounds__(128) void k_attn_reduce(const float* __restrict__ part,
                                                     float* __restrict__ o) {
    int h = blockIdx.x, t = threadIdx.x;
    const float* ph = part + (size_t)h * NSPLIT * PSTRIDE;
    float M = -1e30f;
    float ml[NSPLIT];
    float ll[NSPLIT];
    #pragma unroll
    for (int s = 0; s < NSPLIT; ++s) {
        ml[s] = ph[s * PSTRIDE + DH];
        ll[s] = ph[s * PSTRIDE + DH + 1];
        M = fmaxf(M, ml[s]);
    }
    float L = 0.f, acc = 0.f;
    #pragma unroll
    for (int s = 0; s < NSPLIT; ++s) {
        float w = __expf(ml[s] - M);
        L += ll[s] * w;
        acc += ph[s * PSTRIDE + t] * w;
    }
    o[h * DH + t] = acc / L;
}

extern "C" void kernel_launch(void* const* d_in, const int* in_sizes, int n_in,
                              void* d_out, int out_size, void* d_ws, size_t ws_size,
                              hipStream_t stream) {
    const float* x     = (const float*)d_in[0];
    const float* freqs = (const float*)d_in[1];
    const float* wqkv  = (const float*)d_in[2];
    const float* wo    = (const float*)d_in[3];
    const float* kc    = (const float*)d_in[4];
    const float* vc    = (const float*)d_in[5];
    const int*   ip    = (const int*)d_in[6];
    float* y = (float*)d_out;

    float* ws     = (float*)d_ws;
    float* q1     = ws;                   // 4096
    float* kn     = ws + 4096;            // 4096
    float* vn     = ws + 8192;            // 4096
    float* scores = ws + 12288;           // 65536
    float* part   = ws + 77824;           // 32*8*130 = 33280
    float* o      = ws + 111104;          // 4096
    int*   blkl   = (int*)(ws + 115200);  // 32*192 ints

    // 1) qkv = x @ wqkv.T with fused RoPE -> q1, kn, vn
    k_gemv_qkv<<<3 * DIMM / 4, 256, 0, stream>>>(x, wqkv, freqs, q1, kn, vn);
    // 2) block-mean scores (32 heads * 2048 blocks, 4 blocks per WG)
    k_scores<<<NH * 512, 256, 0, stream>>>(q1, kc, ip, scores);
    // 3) per-head top-k block selection (one wave per head)
    k_topk<<<NH, 64, 0, stream>>>(scores, ip, blkl);
    // 4) gathered attention, split 8-ways per head
    k_attn_part<<<NH * NSPLIT, 256, 0, stream>>>(q1, kc, vc, kn, vn, blkl, ip, part);
    // 5) combine partials
    k_attn_reduce<<<NH, 128, 0, stream>>>(part, o);
    // 6) y = o @ wo.T
    k_gemv_o<<<DIMM / 4, 256, 0, stream>>>(o, wo, y);
}